// Round 1
// baseline (21671.432 us; speedup 1.0000x reference)
//
#include <hip/hip_runtime.h>
#include <hip/hip_bf16.h>
#include <math.h>

// Problem constants (fixed by setup_inputs)
#define TT 1024
#define CC 1024
#define HH 16
#define HD 64
#define FF 4096
#define VV 32000
#define LL 8
#define BBATCH 2
#define MM (BBATCH*TT)   // 2048 rows

// ---------------- embed: x[b,t,:] = tok_emb[idx[b,t],:] + pos_emb[0,t,:] ----------------
__global__ __launch_bounds__(256) void k_embed(const int* __restrict__ idx,
        const float* __restrict__ tok, const float* __restrict__ pos,
        float* __restrict__ x) {
    int i = blockIdx.x * 256 + threadIdx.x;     // index in float4 units over M*C/4
    int c4 = i & (CC/4 - 1);                    // 0..255
    int bt = i >> 8;                            // row 0..2047
    int t  = bt & (TT - 1);
    int tk = idx[bt];
    float4 a = ((const float4*)tok)[(size_t)tk * (CC/4) + c4];
    float4 p = ((const float4*)pos)[(size_t)t  * (CC/4) + c4];
    float4 r; r.x=a.x+p.x; r.y=a.y+p.y; r.z=a.z+p.z; r.w=a.w+p.w;
    ((float4*)x)[i] = r;
}

// ---------------- LayerNorm: one block per row, C=1024, block=256 ----------------
__global__ __launch_bounds__(256) void k_lnorm(const float* __restrict__ x,
        const float* __restrict__ w, const float* __restrict__ b,
        float* __restrict__ out) {
    __shared__ float rs[4], rs2[4];
    int row = blockIdx.x, tid = threadIdx.x;
    float4 xv = ((const float4*)x)[(size_t)row * (CC/4) + tid];
    float s  = xv.x + xv.y + xv.z + xv.w;
    float s2 = xv.x*xv.x + xv.y*xv.y + xv.z*xv.z + xv.w*xv.w;
    #pragma unroll
    for (int off = 32; off > 0; off >>= 1) {
        s  += __shfl_down(s,  off, 64);
        s2 += __shfl_down(s2, off, 64);
    }
    if ((tid & 63) == 0) { rs[tid >> 6] = s; rs2[tid >> 6] = s2; }
    __syncthreads();
    float S  = rs[0] + rs[1] + rs[2] + rs[3];
    float S2 = rs2[0] + rs2[1] + rs2[2] + rs2[3];
    float mu  = S * (1.0f / CC);
    float var = S2 * (1.0f / CC) - mu * mu;
    float rstd = rsqrtf(var + 1e-5f);
    float4 wv = ((const float4*)w)[tid];
    float4 bv = ((const float4*)b)[tid];
    float4 o;
    o.x = (xv.x - mu) * rstd * wv.x + bv.x;
    o.y = (xv.y - mu) * rstd * wv.y + bv.y;
    o.z = (xv.z - mu) * rstd * wv.z + bv.z;
    o.w = (xv.w - mu) * rstd * wv.w + bv.w;
    ((float4*)out)[(size_t)row * (CC/4) + tid] = o;
}

// ---------------- fp32 tiled GEMM: out[M,N] = A[M,K] @ B[K,N] (+bias)(+gelu|+res) ----------------
// mode 0: +bias    mode 1: gelu(+bias)    mode 2: +bias +res
#define GBM 64
#define GBN 64
#define GBK 16

__device__ __forceinline__ float gelu_exact(float v) {
    return 0.5f * v * (1.0f + erff(v * 0.70710678118654752f));
}

__global__ __launch_bounds__(256) void k_gemm(const float* __restrict__ A,
        const float* __restrict__ Bw, const float* __restrict__ bias,
        const float* __restrict__ res, float* __restrict__ out,
        int M, int N, int K, int mode) {
    __shared__ float As[GBK][GBM];   // A^T tile
    __shared__ float Bs[GBK][GBN];
    const int tid = threadIdx.x;
    const int bn = blockIdx.x * GBN;
    const int bm = blockIdx.y * GBM;
    const int ty = tid >> 4, tx = tid & 15;
    const int arow = tid >> 2, acol = (tid & 3) << 2;   // 64 rows x 16 k
    const int brow = tid >> 4, bcol = (tid & 15) << 2;  // 16 k x 64 cols
    float acc[4][4] = {};
    const float* Aptr = A  + (size_t)(bm + arow) * K + acol;
    const float* Bptr = Bw + (size_t)brow * N + bn + bcol;
    for (int k0 = 0; k0 < K; k0 += GBK) {
        float4 av = *(const float4*)(Aptr + k0);
        float4 bv = *(const float4*)(Bptr + (size_t)k0 * N);
        __syncthreads();
        As[acol+0][arow] = av.x;
        As[acol+1][arow] = av.y;
        As[acol+2][arow] = av.z;
        As[acol+3][arow] = av.w;
        *(float4*)&Bs[brow][bcol] = bv;
        __syncthreads();
        #pragma unroll
        for (int k = 0; k < GBK; ++k) {
            float a0 = As[k][ty*4+0], a1 = As[k][ty*4+1];
            float a2 = As[k][ty*4+2], a3 = As[k][ty*4+3];
            float b0 = Bs[k][tx*4+0], b1 = Bs[k][tx*4+1];
            float b2 = Bs[k][tx*4+2], b3 = Bs[k][tx*4+3];
            acc[0][0] += a0*b0; acc[0][1] += a0*b1; acc[0][2] += a0*b2; acc[0][3] += a0*b3;
            acc[1][0] += a1*b0; acc[1][1] += a1*b1; acc[1][2] += a1*b2; acc[1][3] += a1*b3;
            acc[2][0] += a2*b0; acc[2][1] += a2*b1; acc[2][2] += a2*b2; acc[2][3] += a2*b3;
            acc[3][0] += a3*b0; acc[3][1] += a3*b1; acc[3][2] += a3*b2; acc[3][3] += a3*b3;
        }
    }
    float4 bias4 = make_float4(0.f, 0.f, 0.f, 0.f);
    if (bias) bias4 = *(const float4*)(bias + bn + tx*4);
    #pragma unroll
    for (int i = 0; i < 4; ++i) {
        size_t o = (size_t)(bm + ty*4 + i) * N + bn + tx*4;
        float4 v;
        v.x = acc[i][0] + bias4.x;
        v.y = acc[i][1] + bias4.y;
        v.z = acc[i][2] + bias4.z;
        v.w = acc[i][3] + bias4.w;
        if (mode == 1) {
            v.x = gelu_exact(v.x); v.y = gelu_exact(v.y);
            v.z = gelu_exact(v.z); v.w = gelu_exact(v.w);
        } else if (mode == 2) {
            float4 rv = *(const float4*)(res + o);
            v.x += rv.x; v.y += rv.y; v.z += rv.z; v.w += rv.w;
        }
        *(float4*)(out + o) = v;
    }
}

// ---------------- causal attention, one block per (b,h,t); adds result into x ----------------
// q,k,v stored as [B,T,H,hd] (i.e. [M, C] from projection); block=256
__global__ __launch_bounds__(256) void k_attn(const float* __restrict__ q,
        const float* __restrict__ kk, const float* __restrict__ vv,
        float* __restrict__ x) {
    const int t = blockIdx.x, h = blockIdx.y, b = blockIdx.z;
    const int tid = threadIdx.x;
    __shared__ float sc[TT];
    __shared__ float qs[HD];
    __shared__ float red[4];
    __shared__ float ys[4][HD];
    const size_t rowoff = ((size_t)(b*TT + t)) * CC + h*HD;
    if (tid < 16) ((float4*)qs)[tid] = *(const float4*)(q + rowoff + tid*4);
    __syncthreads();
    const int nk = t + 1;
    const float scale = 0.125f;  // 1/sqrt(64)
    for (int s = tid; s < nk; s += 256) {
        const float* kr = kk + ((size_t)(b*TT + s)) * CC + h*HD;
        float acc = 0.f;
        #pragma unroll
        for (int d = 0; d < HD; d += 4) {
            float4 kv = *(const float4*)(kr + d);
            acc += qs[d]*kv.x + qs[d+1]*kv.y + qs[d+2]*kv.z + qs[d+3]*kv.w;
        }
        sc[s] = acc * scale;
    }
    __syncthreads();
    // max
    float m = -3.4e38f;
    for (int s = tid; s < nk; s += 256) m = fmaxf(m, sc[s]);
    #pragma unroll
    for (int off = 32; off > 0; off >>= 1) m = fmaxf(m, __shfl_down(m, off, 64));
    if ((tid & 63) == 0) red[tid >> 6] = m;
    __syncthreads();
    m = fmaxf(fmaxf(red[0], red[1]), fmaxf(red[2], red[3]));
    __syncthreads();  // red about to be reused
    // exp + sum (each thread rewrites only its own sc[s])
    float sum = 0.f;
    for (int s = tid; s < nk; s += 256) {
        float e = expf(sc[s] - m);
        sc[s] = e;
        sum += e;
    }
    #pragma unroll
    for (int off = 32; off > 0; off >>= 1) sum += __shfl_down(sum, off, 64);
    if ((tid & 63) == 0) red[tid >> 6] = sum;
    __syncthreads();  // also guarantees all sc[] exp writes visible
    sum = red[0] + red[1] + red[2] + red[3];
    float inv = 1.0f / sum;
    // y[d] = sum_s p[s] * v[s,d]; threads = 4 chunks x 64 dims (coalesced v reads)
    const int d = tid & 63, ch = tid >> 6;
    float yd = 0.f;
    for (int s = ch; s < nk; s += 4)
        yd += sc[s] * vv[((size_t)(b*TT + s)) * CC + h*HD + d];
    ys[ch][d] = yd;
    __syncthreads();
    if (tid < 64) {
        float r = (ys[0][tid] + ys[1][tid] + ys[2][tid] + ys[3][tid]) * inv;
        x[rowoff + tid] += r;
    }
}

extern "C" void kernel_launch(void* const* d_in, const int* in_sizes, int n_in,
                              void* d_out, int out_size, void* d_ws, size_t ws_size,
                              hipStream_t stream) {
    const int*   idx   = (const int*)  d_in[0];
    const float* tok   = (const float*)d_in[1];
    const float* pos   = (const float*)d_in[2];
    const float* ln1w  = (const float*)d_in[3];
    const float* ln1b  = (const float*)d_in[4];
    const float* wq    = (const float*)d_in[5];
    const float* bq    = (const float*)d_in[6];
    const float* wk    = (const float*)d_in[7];
    const float* bk    = (const float*)d_in[8];
    const float* wv    = (const float*)d_in[9];
    const float* bv    = (const float*)d_in[10];
    const float* ln2w  = (const float*)d_in[11];
    const float* ln2b  = (const float*)d_in[12];
    const float* w1    = (const float*)d_in[13];
    const float* b1    = (const float*)d_in[14];
    const float* w2    = (const float*)d_in[15];
    const float* b2    = (const float*)d_in[16];
    const float* lnfw  = (const float*)d_in[17];
    const float* lnfb  = (const float*)d_in[18];
    const float* headw = (const float*)d_in[19];
    float* out = (float*)d_out;

    // workspace layout (floats): x[2Mi] | h[2Mi] | overlay{ q,k,v (3x2Mi) | ffn (8Mi) }
    float* ws = (float*)d_ws;
    const size_t MC = (size_t)MM * CC;   // 2 Mi floats
    float* x    = ws;
    float* hbuf = ws + MC;
    float* qb   = ws + 2*MC;
    float* kb   = qb + MC;
    float* vb   = kb + MC;
    float* ffn  = qb;                    // reused after attention, needs MM*FF floats

    k_embed<<<(MM*CC/4)/256, 256, 0, stream>>>(idx, tok, pos, x);

    dim3 gProj(CC/GBN, MM/GBM);    // 16 x 32
    dim3 gFfn1(FF/GBN, MM/GBM);    // 64 x 32
    dim3 gFfn2(CC/GBN, MM/GBM);
    dim3 gAttn(TT, HH, BBATCH);

    for (int l = 0; l < LL; ++l) {
        k_lnorm<<<MM, 256, 0, stream>>>(x, ln1w + l*CC, ln1b + l*CC, hbuf);
        k_gemm<<<gProj, 256, 0, stream>>>(hbuf, wq + (size_t)l*CC*CC, bq + l*CC, nullptr, qb, MM, CC, CC, 0);
        k_gemm<<<gProj, 256, 0, stream>>>(hbuf, wk + (size_t)l*CC*CC, bk + l*CC, nullptr, kb, MM, CC, CC, 0);
        k_gemm<<<gProj, 256, 0, stream>>>(hbuf, wv + (size_t)l*CC*CC, bv + l*CC, nullptr, vb, MM, CC, CC, 0);
        k_attn<<<gAttn, 256, 0, stream>>>(qb, kb, vb, x);
        k_lnorm<<<MM, 256, 0, stream>>>(x, ln2w + l*CC, ln2b + l*CC, hbuf);
        k_gemm<<<gFfn1, 256, 0, stream>>>(hbuf, w1 + (size_t)l*CC*FF, b1 + l*FF, nullptr, ffn, MM, FF, CC, 1);
        k_gemm<<<gFfn2, 256, 0, stream>>>(ffn, w2 + (size_t)l*FF*CC, b2 + l*CC, x, x, MM, CC, FF, 2);
    }
    k_lnorm<<<MM, 256, 0, stream>>>(x, lnfw, lnfb, hbuf);
    k_gemm<<<dim3(VV/GBN, MM/GBM), 256, 0, stream>>>(hbuf, headw, nullptr, nullptr, out, MM, VV, CC, 0);
}